// Round 1
// baseline (352.049 us; speedup 1.0000x reference)
//
#include <hip/hip_runtime.h>
#include <hip/hip_bf16.h>
#include <math.h>

#define PAST 8191
#define SCALEF 0.0625f  // 256^-0.5

using bf = __hip_bfloat16;

__device__ __forceinline__ float bf2f(unsigned short u) {
    return __uint_as_float(((unsigned)u) << 16);
}
__device__ __forceinline__ void unpack8(uint4 r, float* f) {
    f[0] = __uint_as_float(r.x << 16);
    f[1] = __uint_as_float(r.x & 0xffff0000u);
    f[2] = __uint_as_float(r.y << 16);
    f[3] = __uint_as_float(r.y & 0xffff0000u);
    f[4] = __uint_as_float(r.z << 16);
    f[5] = __uint_as_float(r.z & 0xffff0000u);
    f[6] = __uint_as_float(r.w << 16);
    f[7] = __uint_as_float(r.w & 0xffff0000u);
}

// ---- dtype-generic loaders: BF16=true -> packed bf16, else fp32 ----
template<bool BF16>
__device__ __forceinline__ void load8(const void* W, size_t off, float* f) {
    if constexpr (BF16) {
        uint4 r = *reinterpret_cast<const uint4*>((const unsigned short*)W + off);
        unpack8(r, f);
    } else {
        const float* p = (const float*)W + off;
        float4 a = *reinterpret_cast<const float4*>(p);
        float4 b = *reinterpret_cast<const float4*>(p + 4);
        f[0]=a.x; f[1]=a.y; f[2]=a.z; f[3]=a.w;
        f[4]=b.x; f[5]=b.y; f[6]=b.z; f[7]=b.w;
    }
}
template<bool BF16>
__device__ __forceinline__ void load4(const void* P, size_t off, float* f) {
    if constexpr (BF16) {
        uint2 r = *reinterpret_cast<const uint2*>((const unsigned short*)P + off);
        f[0] = __uint_as_float(r.x << 16); f[1] = __uint_as_float(r.x & 0xffff0000u);
        f[2] = __uint_as_float(r.y << 16); f[3] = __uint_as_float(r.y & 0xffff0000u);
    } else {
        float4 a = *reinterpret_cast<const float4*>((const float*)P + off);
        f[0]=a.x; f[1]=a.y; f[2]=a.z; f[3]=a.w;
    }
}
template<bool BF16>
__device__ __forceinline__ float load1(const void* P, int i) {
    if constexpr (BF16) return bf2f(((const unsigned short*)P)[i]);
    else return ((const float*)P)[i];
}

// ---- dtype probe: inspect first 768 words of x (in-bounds for both dtypes) ----
__global__ __launch_bounds__(256) void probe_kernel(const unsigned int* __restrict__ xw,
                                                    int* __restrict__ flag) {
    __shared__ int cnt;
    if (threadIdx.x == 0) cnt = 0;
    __syncthreads();
    int ok = 0;
    for (int i = threadIdx.x; i < 768; i += 256) {
        unsigned e = (xw[i] >> 7) & 0xff;  // exponent field of LOW 16 bits as bf16
        if (e >= 96 && e <= 142) ok++;
    }
    atomicAdd(&cnt, ok);
    __syncthreads();
    if (threadIdx.x == 0) *flag = (cnt > 500) ? 1 : 0;
}

// ---------------- QKV projection: grid (5, 96) x 64, 16-row chunks ----------------
template<bool BF16>
__device__ void qkv_body(const void* __restrict__ x, const void* __restrict__ Wq,
                         const void* __restrict__ bq, const void* __restrict__ Wk,
                         const void* __restrict__ bk, const void* __restrict__ Wv,
                         const void* __restrict__ bv, float* __restrict__ qkv) {
    __shared__ float xs[16];
    int tid = threadIdx.x;
    int i0 = blockIdx.y * 16;
    if (tid < 16) xs[tid] = load1<BF16>(x, i0 + tid);
    __syncthreads();
    int j = blockIdx.x * 512 + tid * 8;
    const void* W; const void* bias; int stride, jl;
    if (j < 2048)      { W = Wq; bias = bq; stride = 2048; jl = j; }
    else if (j < 2304) { W = Wk; bias = bk; stride = 256;  jl = j - 2048; }
    else               { W = Wv; bias = bv; stride = 256;  jl = j - 2304; }
    float acc[8] = {0,0,0,0,0,0,0,0};
    #pragma unroll 4
    for (int i = 0; i < 16; ++i) {
        float f[8];
        load8<BF16>(W, (size_t)(i0 + i) * stride + jl, f);
        float xv = xs[i];
        #pragma unroll
        for (int q = 0; q < 8; ++q) acc[q] = fmaf(xv, f[q], acc[q]);
    }
    if (blockIdx.y == 0) {
        #pragma unroll
        for (int q = 0; q < 8; ++q) acc[q] += load1<BF16>(bias, jl + q);
    }
    #pragma unroll
    for (int q = 0; q < 8; ++q) atomicAdd(&qkv[j + q], acc[q]);
}
__global__ __launch_bounds__(64) void qkv_kernel(
    const void* x, const void* Wq, const void* bq, const void* Wk, const void* bk,
    const void* Wv, const void* bv, float* qkv, const int* flag) {
    if (*flag) qkv_body<true>(x, Wq, bq, Wk, bk, Wv, bv, qkv);
    else       qkv_body<false>(x, Wq, bq, Wk, bk, Wv, bv, qkv);
}

// ---------------- scores: grid 2048 x 256 (4 positions/block) ----------------
template<bool BF16>
__device__ void scores_body(const float* __restrict__ qkv, const void* __restrict__ k_past,
                            float* __restrict__ s) {
    int wave = threadIdx.x >> 6, lane = threadIdx.x & 63;
    int p = blockIdx.x * 4 + wave;
    int d0 = lane * 4;
    float kf[4];
    if (p < PAST) {
        load4<BF16>(k_past, (size_t)p * 256 + d0, kf);
    } else {
        kf[0] = qkv[2048 + d0];     kf[1] = qkv[2048 + d0 + 1];
        kf[2] = qkv[2048 + d0 + 2]; kf[3] = qkv[2048 + d0 + 3];
    }
    float part[8];
    #pragma unroll
    for (int h = 0; h < 8; ++h) {
        const float* qh = qkv + h * 256 + d0;
        part[h] = qh[0]*kf[0] + qh[1]*kf[1] + qh[2]*kf[2] + qh[3]*kf[3];
    }
    #pragma unroll
    for (int m = 1; m < 64; m <<= 1) {
        #pragma unroll
        for (int h = 0; h < 8; ++h) part[h] += __shfl_xor(part[h], m, 64);
    }
    if (lane == 0) {
        #pragma unroll
        for (int h = 0; h < 8; ++h) s[h * 8192 + p] = part[h] * SCALEF;
    }
}
__global__ __launch_bounds__(256) void scores_kernel(
    const float* qkv, const void* k_past, float* s, const int* flag) {
    if (*flag) scores_body<true>(qkv, k_past, s);
    else       scores_body<false>(qkv, k_past, s);
}

// ---------------- per-head max + sum-of-exp (no softmax materialization) ----------------
__global__ __launch_bounds__(256) void mred_kernel(
    const float* __restrict__ s, float* __restrict__ ml) {
    __shared__ float red[256];
    int h = blockIdx.x, tid = threadIdx.x;
    const float* sh = s + h * 8192;
    float m = -1e30f;
    for (int p = tid; p < 8192; p += 256) m = fmaxf(m, sh[p]);
    red[tid] = m; __syncthreads();
    for (int w = 128; w > 0; w >>= 1) {
        if (tid < w) red[tid] = fmaxf(red[tid], red[tid + w]);
        __syncthreads();
    }
    m = red[0]; __syncthreads();
    float l = 0.f;
    for (int p = tid; p < 8192; p += 256) l += expf(sh[p] - m);
    red[tid] = l; __syncthreads();
    for (int w = 128; w > 0; w >>= 1) {
        if (tid < w) red[tid] += red[tid + w];
        __syncthreads();
    }
    if (tid == 0) { ml[2 * h] = m; ml[2 * h + 1] = red[0]; }
}

// ---------------- PV: grid 128 x 256, exp fused, atomic into attnout ----------------
template<bool BF16>
__device__ void pv_body(const float* __restrict__ s, const float* __restrict__ ml,
                        const void* __restrict__ v_past, const float* __restrict__ qkv,
                        float* __restrict__ attnout) {
    __shared__ float red[3 * 2048];
    int wave = threadIdx.x >> 6, lane = threadIdx.x & 63;
    int d0 = lane * 4;
    float m[8];
    #pragma unroll
    for (int h = 0; h < 8; ++h) m[h] = ml[2 * h];
    float o[8][4];
    #pragma unroll
    for (int h = 0; h < 8; ++h)
        #pragma unroll
        for (int r = 0; r < 4; ++r) o[h][r] = 0.f;
    int base = blockIdx.x * 64;
    for (int it = 0; it < 16; ++it) {
        int p = base + wave * 16 + it;
        float vf[4];
        if (p < PAST) {
            load4<BF16>(v_past, (size_t)p * 256 + d0, vf);
        } else {
            vf[0] = qkv[2304 + d0];     vf[1] = qkv[2304 + d0 + 1];
            vf[2] = qkv[2304 + d0 + 2]; vf[3] = qkv[2304 + d0 + 3];
        }
        #pragma unroll
        for (int h = 0; h < 8; ++h) {
            float w = expf(s[h * 8192 + p] - m[h]);
            #pragma unroll
            for (int r = 0; r < 4; ++r) o[h][r] = fmaf(w, vf[r], o[h][r]);
        }
    }
    if (wave > 0) {
        float* dst = red + (wave - 1) * 2048;
        #pragma unroll
        for (int h = 0; h < 8; ++h)
            #pragma unroll
            for (int r = 0; r < 4; ++r) dst[h * 256 + d0 + r] = o[h][r];
    }
    __syncthreads();
    if (wave == 0) {
        #pragma unroll
        for (int h = 0; h < 8; ++h)
            #pragma unroll
            for (int r = 0; r < 4; ++r) {
                float v = o[h][r] + red[h*256 + d0 + r] + red[2048 + h*256 + d0 + r]
                        + red[4096 + h*256 + d0 + r];
                atomicAdd(&attnout[h * 256 + d0 + r], v);
            }
    }
}
__global__ __launch_bounds__(256) void pv_kernel(
    const float* s, const float* ml, const void* v_past, const float* qkv,
    float* attnout, const int* flag) {
    if (*flag) pv_body<true>(s, ml, v_past, qkv, attnout);
    else       pv_body<false>(s, ml, v_past, qkv, attnout);
}

// ---------------- O projection + residual: grid (3, 128) x 64, 16-row chunks ----------------
template<bool BF16>
__device__ void oproj_body(const float* __restrict__ attnout, const float* __restrict__ ml,
                           const void* __restrict__ Wo, const void* __restrict__ bo,
                           const void* __restrict__ xin, float* __restrict__ x2) {
    __shared__ float xs[16];
    int tid = threadIdx.x;
    int i0 = blockIdx.y * 16;
    if (tid < 16) {
        int i = i0 + tid;
        xs[tid] = attnout[i] * (1.0f / ml[2 * (i >> 8) + 1]);
    }
    __syncthreads();
    int j = blockIdx.x * 512 + tid * 8;
    float acc[8] = {0,0,0,0,0,0,0,0};
    #pragma unroll 4
    for (int i = 0; i < 16; ++i) {
        float f[8];
        load8<BF16>(Wo, (size_t)(i0 + i) * 1536 + j, f);
        float xv = xs[i];
        #pragma unroll
        for (int q = 0; q < 8; ++q) acc[q] = fmaf(xv, f[q], acc[q]);
    }
    if (blockIdx.y == 0) {
        #pragma unroll
        for (int q = 0; q < 8; ++q)
            acc[q] += load1<BF16>(bo, j + q) + load1<BF16>(xin, j + q);
    }
    #pragma unroll
    for (int q = 0; q < 8; ++q) atomicAdd(&x2[j + q], acc[q]);
}
__global__ __launch_bounds__(64) void oproj_kernel(
    const float* attnout, const float* ml, const void* Wo, const void* bo,
    const void* xin, float* x2, const int* flag) {
    if (*flag) oproj_body<true>(attnout, ml, Wo, bo, xin, x2);
    else       oproj_body<false>(attnout, ml, Wo, bo, xin, x2);
}

// ---------------- gate/up GEMV: grid (12, 48, 2) x 64, 32-row chunks ----------------
template<bool BF16>
__device__ void gateup_body(const float* __restrict__ x2, const void* __restrict__ Wg,
                            const void* __restrict__ Wu, float* __restrict__ gacc,
                            float* __restrict__ uacc) {
    __shared__ float xs[32];
    int tid = threadIdx.x; int i0 = blockIdx.y * 32;
    if (tid < 32) xs[tid] = x2[i0 + tid];
    __syncthreads();
    const void* W = blockIdx.z ? Wu : Wg;
    float* acc = blockIdx.z ? uacc : gacc;
    int j = blockIdx.x * 512 + tid * 8;
    float a[8] = {0,0,0,0,0,0,0,0};
    #pragma unroll 4
    for (int i = 0; i < 32; ++i) {
        float f[8];
        load8<BF16>(W, (size_t)(i0 + i) * 6144 + j, f);
        float xv = xs[i];
        #pragma unroll
        for (int q = 0; q < 8; ++q) a[q] = fmaf(xv, f[q], a[q]);
    }
    #pragma unroll
    for (int q = 0; q < 8; ++q) atomicAdd(&acc[j + q], a[q]);
}
__global__ __launch_bounds__(64) void gateup_kernel(
    const float* x2, const void* Wg, const void* Wu, float* gacc, float* uacc,
    const int* flag) {
    if (*flag) gateup_body<true>(x2, Wg, Wu, gacc, uacc);
    else       gateup_body<false>(x2, Wg, Wu, gacc, uacc);
}

// ---------------- down GEMV with fused GELU(g)*u: grid (3, 192) x 64, 32-row chunks ----------------
template<bool BF16>
__device__ void down_body(const float* __restrict__ gacc, const float* __restrict__ uacc,
                          const void* __restrict__ bg, const void* __restrict__ bu,
                          const void* __restrict__ Wd, float* __restrict__ yacc) {
    __shared__ float xs[32];
    int tid = threadIdx.x; int i0 = blockIdx.y * 32;
    if (tid < 32) {
        int i = i0 + tid;
        float g = gacc[i] + load1<BF16>(bg, i);
        float u = uacc[i] + load1<BF16>(bu, i);
        float ge = 0.5f * g * (1.0f + erff(g * 0.70710678118654752f));
        xs[tid] = ge * u;
    }
    __syncthreads();
    int j = blockIdx.x * 512 + tid * 8;
    float a[8] = {0,0,0,0,0,0,0,0};
    #pragma unroll 4
    for (int i = 0; i < 32; ++i) {
        float f[8];
        load8<BF16>(Wd, (size_t)(i0 + i) * 1536 + j, f);
        float xv = xs[i];
        #pragma unroll
        for (int q = 0; q < 8; ++q) a[q] = fmaf(xv, f[q], a[q]);
    }
    #pragma unroll
    for (int q = 0; q < 8; ++q) atomicAdd(&yacc[j + q], a[q]);
}
__global__ __launch_bounds__(64) void down_kernel(
    const float* gacc, const float* uacc, const void* bg, const void* bu,
    const void* Wd, float* yacc, const int* flag) {
    if (*flag) down_body<true>(gacc, uacc, bg, bu, Wd, yacc);
    else       down_body<false>(gacc, uacc, bg, bu, Wd, yacc);
}

// ---------------- final: out = (x2 + y + bd) in the input dtype ----------------
__global__ __launch_bounds__(256) void final_kernel(
    const float* __restrict__ x2, const float* __restrict__ yacc,
    const void* __restrict__ bd, void* __restrict__ out, const int* __restrict__ flag) {
    int j = blockIdx.x * 256 + threadIdx.x;
    if (j < 1536) {
        int isbf = *flag;
        float b = isbf ? bf2f(((const unsigned short*)bd)[j]) : ((const float*)bd)[j];
        float v = x2[j] + yacc[j] + b;
        if (isbf) ((bf*)out)[j] = __float2bfloat16(v);
        else      ((float*)out)[j] = v;
    }
}

extern "C" void kernel_launch(void* const* d_in, const int* in_sizes, int n_in,
                              void* d_out, int out_size, void* d_ws, size_t ws_size,
                              hipStream_t stream) {
    const void* x  = d_in[0];
    const void* kp = d_in[1];
    const void* vp = d_in[2];
    const void* Wq = d_in[3];
    const void* bq = d_in[4];
    const void* Wk = d_in[5];
    const void* bk = d_in[6];
    const void* Wv = d_in[7];
    const void* bv = d_in[8];
    const void* Wo = d_in[9];
    const void* bo = d_in[10];
    const void* Wg = d_in[11];
    const void* bg = d_in[12];
    const void* Wu = d_in[13];
    const void* bu = d_in[14];
    const void* Wd = d_in[15];
    const void* bd = d_in[16];

    float* ws      = (float*)d_ws;
    float* qkv     = ws;             // 2560
    float* x2      = ws + 2560;      // 1536
    float* gacc    = ws + 4096;      // 6144
    float* uacc    = ws + 10240;     // 6144
    float* yacc    = ws + 16384;     // 1536
    float* attnout = ws + 17920;     // 2048
    float* ml      = ws + 19968;     // 16 (written, not accumulated)
    float* sc      = ws + 20480;     // 65536
    int*  flag     = (int*)(ws + 86016);

    // zero all atomic accumulators (qkv..attnout = 19968 floats)
    hipMemsetAsync(ws, 0, 19968 * sizeof(float), stream);
    probe_kernel<<<1, 256, 0, stream>>>((const unsigned int*)x, flag);

    qkv_kernel<<<dim3(5, 96), 64, 0, stream>>>(x, Wq, bq, Wk, bk, Wv, bv, qkv, flag);
    scores_kernel<<<2048, 256, 0, stream>>>(qkv, kp, sc, flag);
    mred_kernel<<<8, 256, 0, stream>>>(sc, ml);
    pv_kernel<<<128, 256, 0, stream>>>(sc, ml, vp, qkv, attnout, flag);
    oproj_kernel<<<dim3(3, 128), 64, 0, stream>>>(attnout, ml, Wo, bo, x, x2, flag);
    gateup_kernel<<<dim3(12, 48, 2), 64, 0, stream>>>(x2, Wg, Wu, gacc, uacc, flag);
    down_kernel<<<dim3(3, 192), 64, 0, stream>>>(gacc, uacc, bg, bu, Wd, yacc, flag);
    final_kernel<<<6, 256, 0, stream>>>(x2, yacc, bd, d_out, flag);
}

// Round 2
// 278.846 us; speedup vs baseline: 1.2625x; 1.2625x over previous
//
#include <hip/hip_runtime.h>
#include <hip/hip_bf16.h>
#include <math.h>

#define PAST 8191
#define SCALEF 0.0625f  // 256^-0.5

using bf = __hip_bfloat16;

__device__ __forceinline__ float bf2f(unsigned short u) {
    return __uint_as_float(((unsigned)u) << 16);
}
__device__ __forceinline__ void unpack8(uint4 r, float* f) {
    f[0] = __uint_as_float(r.x << 16);
    f[1] = __uint_as_float(r.x & 0xffff0000u);
    f[2] = __uint_as_float(r.y << 16);
    f[3] = __uint_as_float(r.y & 0xffff0000u);
    f[4] = __uint_as_float(r.z << 16);
    f[5] = __uint_as_float(r.z & 0xffff0000u);
    f[6] = __uint_as_float(r.w << 16);
    f[7] = __uint_as_float(r.w & 0xffff0000u);
}

// ---- dtype-generic loaders: BF16=true -> packed bf16, else fp32 ----
template<bool BF16>
__device__ __forceinline__ void load8(const void* W, size_t off, float* f) {
    if constexpr (BF16) {
        uint4 r = *reinterpret_cast<const uint4*>((const unsigned short*)W + off);
        unpack8(r, f);
    } else {
        const float* p = (const float*)W + off;
        float4 a = *reinterpret_cast<const float4*>(p);
        float4 b = *reinterpret_cast<const float4*>(p + 4);
        f[0]=a.x; f[1]=a.y; f[2]=a.z; f[3]=a.w;
        f[4]=b.x; f[5]=b.y; f[6]=b.z; f[7]=b.w;
    }
}
template<bool BF16>
__device__ __forceinline__ void load4(const void* P, size_t off, float* f) {
    if constexpr (BF16) {
        uint2 r = *reinterpret_cast<const uint2*>((const unsigned short*)P + off);
        f[0] = __uint_as_float(r.x << 16); f[1] = __uint_as_float(r.x & 0xffff0000u);
        f[2] = __uint_as_float(r.y << 16); f[3] = __uint_as_float(r.y & 0xffff0000u);
    } else {
        float4 a = *reinterpret_cast<const float4*>((const float*)P + off);
        f[0]=a.x; f[1]=a.y; f[2]=a.z; f[3]=a.w;
    }
}
template<bool BF16>
__device__ __forceinline__ float load1(const void* P, int i) {
    if constexpr (BF16) return bf2f(((const unsigned short*)P)[i]);
    else return ((const float*)P)[i];
}

// ---- dtype probe ----
__global__ __launch_bounds__(256) void probe_kernel(const unsigned int* __restrict__ xw,
                                                    int* __restrict__ flag) {
    __shared__ int cnt;
    if (threadIdx.x == 0) cnt = 0;
    __syncthreads();
    int ok = 0;
    for (int i = threadIdx.x; i < 768; i += 256) {
        unsigned e = (xw[i] >> 7) & 0xff;
        if (e >= 96 && e <= 142) ok++;
    }
    atomicAdd(&cnt, ok);
    __syncthreads();
    if (threadIdx.x == 0) *flag = (cnt > 500) ? 1 : 0;
}

// ---- GEMV core: 32 rows per wave, 8-deep independent load pipeline ----
// Loads 8 rows' worth of uint4/float4 with NO intervening consumption so the
// compiler issues 8 global_load_dwordx4 back-to-back (128B in flight/thread).
template<bool BF16>
__device__ __forceinline__ void gemv_rows32(const void* __restrict__ W, int ldw,
                                            const float* __restrict__ xs_wave,
                                            int row0, int j, float acc[8]) {
    #pragma unroll
    for (int i = 0; i < 32; i += 8) {
        float f[8][8];
        #pragma unroll
        for (int r = 0; r < 8; ++r)
            load8<BF16>(W, (size_t)(row0 + i + r) * ldw + j, f[r]);
        #pragma unroll
        for (int r = 0; r < 8; ++r) {
            float xv = xs_wave[i + r];
            #pragma unroll
            for (int q = 0; q < 8; ++q) acc[q] = fmaf(xv, f[r][q], acc[q]);
        }
    }
}

// ---- cross-wave reduction: waves 1-3 stage, wave 0 owns the final acc ----
// red: LDS float[3*512]
__device__ __forceinline__ void block_reduce_512(float acc[8], float* red,
                                                 int wave, int lane) {
    if (wave > 0) {
        float* dst = red + (wave - 1) * 512 + lane * 8;
        #pragma unroll
        for (int q = 0; q < 8; ++q) dst[q] = acc[q];
    }
    __syncthreads();
    if (wave == 0) {
        int o = lane * 8;
        #pragma unroll
        for (int q = 0; q < 8; ++q)
            acc[q] += red[o + q] + red[512 + o + q] + red[1024 + o + q];
    }
}

// ---------------- QKV projection: grid (5, 12) x 256 ----------------
template<bool BF16>
__device__ void qkv_body(const void* __restrict__ x, const void* __restrict__ Wq,
                         const void* __restrict__ bq, const void* __restrict__ Wk,
                         const void* __restrict__ bk, const void* __restrict__ Wv,
                         const void* __restrict__ bv, float* __restrict__ qkv) {
    __shared__ float xs[128];
    __shared__ float red[3 * 512];
    int tid = threadIdx.x, wave = tid >> 6, lane = tid & 63;
    int i0 = blockIdx.y * 128;
    if (tid < 128) xs[tid] = load1<BF16>(x, i0 + tid);
    __syncthreads();
    int j = blockIdx.x * 512 + lane * 8;
    const void* W; const void* bias; int ldw, jl;
    if (j < 2048)      { W = Wq; bias = bq; ldw = 2048; jl = j; }
    else if (j < 2304) { W = Wk; bias = bk; ldw = 256;  jl = j - 2048; }
    else               { W = Wv; bias = bv; ldw = 256;  jl = j - 2304; }
    float acc[8] = {0,0,0,0,0,0,0,0};
    gemv_rows32<BF16>(W, ldw, xs + wave * 32, i0 + wave * 32, jl, acc);
    block_reduce_512(acc, red, wave, lane);
    if (wave == 0) {
        if (blockIdx.y == 0) {
            #pragma unroll
            for (int q = 0; q < 8; ++q) acc[q] += load1<BF16>(bias, jl + q);
        }
        #pragma unroll
        for (int q = 0; q < 8; ++q) atomicAdd(&qkv[j + q], acc[q]);
    }
}
__global__ __launch_bounds__(256) void qkv_kernel(
    const void* x, const void* Wq, const void* bq, const void* Wk, const void* bk,
    const void* Wv, const void* bv, float* qkv, const int* flag) {
    if (*flag) qkv_body<true>(x, Wq, bq, Wk, bk, Wv, bv, qkv);
    else       qkv_body<false>(x, Wq, bq, Wk, bk, Wv, bv, qkv);
}

// ---------------- scores: grid 2048 x 256 ----------------
template<bool BF16>
__device__ void scores_body(const float* __restrict__ qkv, const void* __restrict__ k_past,
                            float* __restrict__ s) {
    int wave = threadIdx.x >> 6, lane = threadIdx.x & 63;
    int p = blockIdx.x * 4 + wave;
    int d0 = lane * 4;
    float kf[4];
    if (p < PAST) {
        load4<BF16>(k_past, (size_t)p * 256 + d0, kf);
    } else {
        kf[0] = qkv[2048 + d0];     kf[1] = qkv[2048 + d0 + 1];
        kf[2] = qkv[2048 + d0 + 2]; kf[3] = qkv[2048 + d0 + 3];
    }
    float part[8];
    #pragma unroll
    for (int h = 0; h < 8; ++h) {
        const float* qh = qkv + h * 256 + d0;
        part[h] = qh[0]*kf[0] + qh[1]*kf[1] + qh[2]*kf[2] + qh[3]*kf[3];
    }
    #pragma unroll
    for (int m = 1; m < 64; m <<= 1) {
        #pragma unroll
        for (int h = 0; h < 8; ++h) part[h] += __shfl_xor(part[h], m, 64);
    }
    if (lane == 0) {
        #pragma unroll
        for (int h = 0; h < 8; ++h) s[h * 8192 + p] = part[h] * SCALEF;
    }
}
__global__ __launch_bounds__(256) void scores_kernel(
    const float* qkv, const void* k_past, float* s, const int* flag) {
    if (*flag) scores_body<true>(qkv, k_past, s);
    else       scores_body<false>(qkv, k_past, s);
}

// ---------------- per-head max + sum-of-exp ----------------
__global__ __launch_bounds__(256) void mred_kernel(
    const float* __restrict__ s, float* __restrict__ ml) {
    __shared__ float red[256];
    int h = blockIdx.x, tid = threadIdx.x;
    const float* sh = s + h * 8192;
    float m = -1e30f;
    for (int p = tid; p < 8192; p += 256) m = fmaxf(m, sh[p]);
    red[tid] = m; __syncthreads();
    for (int w = 128; w > 0; w >>= 1) {
        if (tid < w) red[tid] = fmaxf(red[tid], red[tid + w]);
        __syncthreads();
    }
    m = red[0]; __syncthreads();
    float l = 0.f;
    for (int p = tid; p < 8192; p += 256) l += expf(sh[p] - m);
    red[tid] = l; __syncthreads();
    for (int w = 128; w > 0; w >>= 1) {
        if (tid < w) red[tid] += red[tid + w];
        __syncthreads();
    }
    if (tid == 0) { ml[2 * h] = m; ml[2 * h + 1] = red[0]; }
}

// ---------------- PV: grid 64 x 256 ----------------
// exp(s-m) computed ONCE per (h,pos) into LDS (round-1 recomputed it in all 64
// lanes); V loads 4-deep independent; 128 positions/block, 32/wave.
template<bool BF16>
__device__ void pv_body(const float* __restrict__ s, const float* __restrict__ ml,
                        const void* __restrict__ v_past, const float* __restrict__ qkv,
                        float* __restrict__ attnout) {
    __shared__ float ss[1024];       // [h][128] pre-exp'd weights
    __shared__ float red[3 * 2048];
    int tid = threadIdx.x, wave = tid >> 6, lane = tid & 63;
    int base = blockIdx.x * 128;
    #pragma unroll
    for (int idx = tid; idx < 1024; idx += 256) {
        int h = idx >> 7, t = idx & 127;
        ss[idx] = expf(s[h * 8192 + base + t] - ml[2 * h]);
    }
    __syncthreads();
    int d0 = lane * 4;
    float o[8][4];
    #pragma unroll
    for (int h = 0; h < 8; ++h)
        #pragma unroll
        for (int r = 0; r < 4; ++r) o[h][r] = 0.f;
    int p0 = base + wave * 32;
    for (int it = 0; it < 32; it += 4) {
        float vf[4][4];
        if (p0 + it + 3 < PAST) {
            #pragma unroll
            for (int r = 0; r < 4; ++r)
                load4<BF16>(v_past, (size_t)(p0 + it + r) * 256 + d0, vf[r]);
        } else {
            #pragma unroll
            for (int r = 0; r < 4; ++r) {
                int p = p0 + it + r;
                if (p < PAST) {
                    load4<BF16>(v_past, (size_t)p * 256 + d0, vf[r]);
                } else {
                    vf[r][0] = qkv[2304 + d0];     vf[r][1] = qkv[2304 + d0 + 1];
                    vf[r][2] = qkv[2304 + d0 + 2]; vf[r][3] = qkv[2304 + d0 + 3];
                }
            }
        }
        #pragma unroll
        for (int r = 0; r < 4; ++r) {
            int t = wave * 32 + it + r;
            #pragma unroll
            for (int h = 0; h < 8; ++h) {
                float w = ss[h * 128 + t];
                #pragma unroll
                for (int rr = 0; rr < 4; ++rr) o[h][rr] = fmaf(w, vf[r][rr], o[h][rr]);
            }
        }
    }
    if (wave > 0) {
        float* dst = red + (wave - 1) * 2048;
        #pragma unroll
        for (int h = 0; h < 8; ++h)
            #pragma unroll
            for (int r = 0; r < 4; ++r) dst[h * 256 + d0 + r] = o[h][r];
    }
    __syncthreads();
    if (wave == 0) {
        #pragma unroll
        for (int h = 0; h < 8; ++h)
            #pragma unroll
            for (int r = 0; r < 4; ++r) {
                float v = o[h][r] + red[h*256 + d0 + r] + red[2048 + h*256 + d0 + r]
                        + red[4096 + h*256 + d0 + r];
                atomicAdd(&attnout[h * 256 + d0 + r], v);
            }
    }
}
__global__ __launch_bounds__(256) void pv_kernel(
    const float* s, const float* ml, const void* v_past, const float* qkv,
    float* attnout, const int* flag) {
    if (*flag) pv_body<true>(s, ml, v_past, qkv, attnout);
    else       pv_body<false>(s, ml, v_past, qkv, attnout);
}

// ---------------- O projection + residual: grid (3, 16) x 256 ----------------
template<bool BF16>
__device__ void oproj_body(const float* __restrict__ attnout, const float* __restrict__ ml,
                           const void* __restrict__ Wo, const void* __restrict__ bo,
                           const void* __restrict__ xin, float* __restrict__ x2) {
    __shared__ float xs[128];
    __shared__ float red[3 * 512];
    int tid = threadIdx.x, wave = tid >> 6, lane = tid & 63;
    int i0 = blockIdx.y * 128;
    if (tid < 128) {
        int i = i0 + tid;
        xs[tid] = attnout[i] * (1.0f / ml[2 * (i >> 8) + 1]);
    }
    __syncthreads();
    int j = blockIdx.x * 512 + lane * 8;
    float acc[8] = {0,0,0,0,0,0,0,0};
    gemv_rows32<BF16>(Wo, 1536, xs + wave * 32, i0 + wave * 32, j, acc);
    block_reduce_512(acc, red, wave, lane);
    if (wave == 0) {
        if (blockIdx.y == 0) {
            #pragma unroll
            for (int q = 0; q < 8; ++q)
                acc[q] += load1<BF16>(bo, j + q) + load1<BF16>(xin, j + q);
        }
        #pragma unroll
        for (int q = 0; q < 8; ++q) atomicAdd(&x2[j + q], acc[q]);
    }
}
__global__ __launch_bounds__(256) void oproj_kernel(
    const float* attnout, const float* ml, const void* Wo, const void* bo,
    const void* xin, float* x2, const int* flag) {
    if (*flag) oproj_body<true>(attnout, ml, Wo, bo, xin, x2);
    else       oproj_body<false>(attnout, ml, Wo, bo, xin, x2);
}

// ---------------- gate/up GEMV: grid (12, 12, 2) x 256 ----------------
template<bool BF16>
__device__ void gateup_body(const float* __restrict__ x2, const void* __restrict__ Wg,
                            const void* __restrict__ Wu, float* __restrict__ gacc,
                            float* __restrict__ uacc) {
    __shared__ float xs[128];
    __shared__ float red[3 * 512];
    int tid = threadIdx.x, wave = tid >> 6, lane = tid & 63;
    int i0 = blockIdx.y * 128;
    if (tid < 128) xs[tid] = x2[i0 + tid];
    __syncthreads();
    const void* W = blockIdx.z ? Wu : Wg;
    float* out = blockIdx.z ? uacc : gacc;
    int j = blockIdx.x * 512 + lane * 8;
    float acc[8] = {0,0,0,0,0,0,0,0};
    gemv_rows32<BF16>(W, 6144, xs + wave * 32, i0 + wave * 32, j, acc);
    block_reduce_512(acc, red, wave, lane);
    if (wave == 0) {
        #pragma unroll
        for (int q = 0; q < 8; ++q) atomicAdd(&out[j + q], acc[q]);
    }
}
__global__ __launch_bounds__(256) void gateup_kernel(
    const float* x2, const void* Wg, const void* Wu, float* gacc, float* uacc,
    const int* flag) {
    if (*flag) gateup_body<true>(x2, Wg, Wu, gacc, uacc);
    else       gateup_body<false>(x2, Wg, Wu, gacc, uacc);
}

// ---------------- down GEMV with fused GELU(g)*u: grid (3, 48) x 256 ----------------
template<bool BF16>
__device__ void down_body(const float* __restrict__ gacc, const float* __restrict__ uacc,
                          const void* __restrict__ bg, const void* __restrict__ bu,
                          const void* __restrict__ Wd, float* __restrict__ yacc) {
    __shared__ float xs[128];
    __shared__ float red[3 * 512];
    int tid = threadIdx.x, wave = tid >> 6, lane = tid & 63;
    int i0 = blockIdx.y * 128;
    if (tid < 128) {
        int i = i0 + tid;
        float g = gacc[i] + load1<BF16>(bg, i);
        float u = uacc[i] + load1<BF16>(bu, i);
        float ge = 0.5f * g * (1.0f + erff(g * 0.70710678118654752f));
        xs[tid] = ge * u;
    }
    __syncthreads();
    int j = blockIdx.x * 512 + lane * 8;
    float acc[8] = {0,0,0,0,0,0,0,0};
    gemv_rows32<BF16>(Wd, 1536, xs + wave * 32, i0 + wave * 32, j, acc);
    block_reduce_512(acc, red, wave, lane);
    if (wave == 0) {
        #pragma unroll
        for (int q = 0; q < 8; ++q) atomicAdd(&yacc[j + q], acc[q]);
    }
}
__global__ __launch_bounds__(256) void down_kernel(
    const float* gacc, const float* uacc, const void* bg, const void* bu,
    const void* Wd, float* yacc, const int* flag) {
    if (*flag) down_body<true>(gacc, uacc, bg, bu, Wd, yacc);
    else       down_body<false>(gacc, uacc, bg, bu, Wd, yacc);
}

// ---------------- final: out = (x2 + y + bd) in the input dtype ----------------
__global__ __launch_bounds__(256) void final_kernel(
    const float* __restrict__ x2, const float* __restrict__ yacc,
    const void* __restrict__ bd, void* __restrict__ out, const int* __restrict__ flag) {
    int j = blockIdx.x * 256 + threadIdx.x;
    if (j < 1536) {
        int isbf = *flag;
        float b = isbf ? bf2f(((const unsigned short*)bd)[j]) : ((const float*)bd)[j];
        float v = x2[j] + yacc[j] + b;
        if (isbf) ((bf*)out)[j] = __float2bfloat16(v);
        else      ((float*)out)[j] = v;
    }
}

extern "C" void kernel_launch(void* const* d_in, const int* in_sizes, int n_in,
                              void* d_out, int out_size, void* d_ws, size_t ws_size,
                              hipStream_t stream) {
    const void* x  = d_in[0];
    const void* kp = d_in[1];
    const void* vp = d_in[2];
    const void* Wq = d_in[3];
    const void* bq = d_in[4];
    const void* Wk = d_in[5];
    const void* bk = d_in[6];
    const void* Wv = d_in[7];
    const void* bv = d_in[8];
    const void* Wo = d_in[9];
    const void* bo = d_in[10];
    const void* Wg = d_in[11];
    const void* bg = d_in[12];
    const void* Wu = d_in[13];
    const void* bu = d_in[14];
    const void* Wd = d_in[15];
    const void* bd = d_in[16];

    float* ws      = (float*)d_ws;
    float* qkv     = ws;             // 2560
    float* x2      = ws + 2560;      // 1536
    float* gacc    = ws + 4096;      // 6144
    float* uacc    = ws + 10240;     // 6144
    float* yacc    = ws + 16384;     // 1536
    float* attnout = ws + 17920;     // 2048
    float* ml      = ws + 19968;     // 16 (written, not accumulated)
    float* sc      = ws + 20480;     // 65536
    int*  flag     = (int*)(ws + 86016);

    hipMemsetAsync(ws, 0, 19968 * sizeof(float), stream);
    probe_kernel<<<1, 256, 0, stream>>>((const unsigned int*)x, flag);

    qkv_kernel<<<dim3(5, 12), 256, 0, stream>>>(x, Wq, bq, Wk, bk, Wv, bv, qkv, flag);
    scores_kernel<<<2048, 256, 0, stream>>>(qkv, kp, sc, flag);
    mred_kernel<<<8, 256, 0, stream>>>(sc, ml);
    pv_kernel<<<64, 256, 0, stream>>>(sc, ml, vp, qkv, attnout, flag);
    oproj_kernel<<<dim3(3, 16), 256, 0, stream>>>(attnout, ml, Wo, bo, x, x2, flag);
    gateup_kernel<<<dim3(12, 12, 2), 256, 0, stream>>>(x2, Wg, Wu, gacc, uacc, flag);
    down_kernel<<<dim3(3, 48), 256, 0, stream>>>(gacc, uacc, bg, bu, Wd, yacc, flag);
    final_kernel<<<6, 256, 0, stream>>>(x2, yacc, bd, d_out, flag);
}